// Round 4
// baseline (288.915 us; speedup 1.0000x reference)
//
#include <hip/hip_runtime.h>
#include <hip/hip_bf16.h>

// Problem constants
constexpr int N   = 32;
constexpr int C   = 16;    // in channels
constexpr int H   = 256;
constexpr int W   = 256;
constexpr int CO  = 16;    // out channels
constexpr int OH  = 254;
constexpr int OW  = 254;
constexpr float SUBV = 0.7f;   // SUB1 + SUB2

// GEMM-view: k = (ky*3+kx)*16 + ci, K=144 padded to 160 (5 chunks of 32)
constexpr int KPAD = 160;

// Tiling
constexpr int TY     = 10;          // output rows per block
constexpr int TIN_Y  = TY + 2;      // 12 staged input rows
constexpr int TX     = 64;          // output px per block (4 waves x 16)
constexpr int TIN_XS = 68;          // staged sites per row (66 needed, 4-aligned)
// Plane-separated LDS: plane h holds ci[8h..8h+7], 16 B/site, no padding.
constexpr int SITE_US = 8;                   // ushorts per site per plane (16 B)
constexpr int ROW_US  = TIN_XS * SITE_US;    // 544 ushorts per row per plane
constexpr int PS      = TIN_Y * ROW_US;      // 6528 ushorts plane stride
// total LDS: 2*PS ushorts = 26112 B

using short8  = __attribute__((ext_vector_type(8))) short;
using floatx4 = __attribute__((ext_vector_type(4))) float;

__device__ inline uint bf16u(float f) {           // RNE float->bf16 bits (inputs are finite)
    uint u = __builtin_bit_cast(uint, f);
    u += 0x7fffu + ((u >> 16) & 1u);
    return u >> 16;
}
__device__ inline uint pkbf(float lo, float hi) { // v_cvt_pk_bf16_f32 (RNE), lo in low 16
    __hip_bfloat162 h = __float22bfloat162_rn(make_float2(lo, hi));
    uint r;
    __builtin_memcpy(&r, &h, sizeof(r));
    return r;
}

// ---------------------------------------------------------------------------
// Kernel 1: weights -> bf16, k-reordered A-matrix [co][KPAD]; k<144 real, rest 0.
// Bias (fp32, -0.7 folded) appended at ushort offset 2560 (byte 5120).
// ---------------------------------------------------------------------------
__global__ void reorder_weights(const float* __restrict__ w,
                                const float* __restrict__ b,
                                ushort* __restrict__ wr) {
    const int t = threadIdx.x;
    for (int i = t; i < CO * KPAD; i += 256) {
        const int co = i / KPAD;
        const int k  = i - co * KPAD;
        ushort v = 0;
        if (k < 144) {
            const int pair = k >> 4;          // ky*3+kx, 0..8
            const int ci   = k & 15;
            const int ky   = pair / 3;
            const int kx   = pair - 3 * ky;
            v = (ushort)bf16u(w[((co * C + ci) * 3 + ky) * 3 + kx]);
        }
        wr[i] = v;
    }
    if (t < CO) ((float*)(wr + CO * KPAD))[t] = b[t] - SUBV;
}

// ---------------------------------------------------------------------------
// Kernel 2: implicit-GEMM conv3x3 via bf16 MFMA 16x16x32, fused bias+mish.
// Block 256 thr = 4 waves. Wave w owns the 16-px column [x0+16w, +16).
// Staging: one 4-site quad per thread (204 active), ALL 16 dwordx4 issued
// before a sched_barrier(0) fence -> 52 KB/block in flight (the compiler
// otherwise sinks loads into the convert phase, ~2 in flight, VGPR=48).
// ---------------------------------------------------------------------------
__launch_bounds__(256, 4)
__global__ void conv_mfma(const float* __restrict__ x,
                          const ushort* __restrict__ wr,
                          float* __restrict__ out) {
    __shared__ ushort lds[2 * PS];           // 26112 B

    const int tid  = threadIdx.x;
    const int lane = tid & 63;
    const int wave = tid >> 6;
    const int quad = lane >> 4;
    const int n    = lane & 15;              // pixel within 16-px tile / co for A load

    const int x0 = blockIdx.x * TX;
    const int y0 = blockIdx.y * TY;
    const int ni = blockIdx.z;

    // ---- stage, phase 1: issue all 16 plane loads (1 KB/lane in flight) ----
    const bool active = tid < TIN_Y * (TIN_XS / 4);   // 204 threads
    int yy = 0, qx = 0;
    float4 v[16];
    if (active) {
        yy = tid / 17;
        qx = tid - yy * 17;
        const int iy = (y0 + yy < H - 1) ? (y0 + yy) : (H - 1);   // clamped rows feed only masked oy
        int bx = x0 + qx * 4;
        if (bx > W - 4) bx = W - 4;                               // clamped quads feed only masked ox
        const float* src = x + (size_t)ni * C * H * W + (size_t)iy * W + bx;
        #pragma unroll
        for (int ci = 0; ci < C; ++ci)
            v[ci] = *(const float4*)(src + (size_t)ci * H * W);
    }
    // Phase fence: nothing may cross. All 16 loads are issued above; the
    // convert/LDS-write phase (and its waitcnts) stays below -> full-batch MLP.
    __builtin_amdgcn_sched_barrier(0);

    // ---- per-lane A fragments / bias / offsets (overlaps load latency) ----
    short8 afrag[5];
    {
        const ushort* wbase = wr + n * KPAD + quad * 8;   // A[m=co=n][k=32c+8*quad+j]
        #pragma unroll
        for (int c = 0; c < 5; ++c)
            afrag[c] = *(const short8*)(wbase + c * 32);
    }
    float bias_j[4];
    {
        const float* bp = (const float*)(wr + CO * KPAD);
        const float4 bv = *(const float4*)(bp + quad * 4);
        bias_j[0] = bv.x; bias_j[1] = bv.y; bias_j[2] = bv.z; bias_j[3] = bv.w;
    }
    int boff[5];
    #pragma unroll
    for (int c = 0; c < 5; ++c) {
        int pair = 2 * c + (quad >> 1);
        if (pair > 8) pair = 8;              // pad chunk reads real data x zero weights
        const int ky = pair / 3;
        const int kx = pair - 3 * ky;
        boff[c] = (quad & 1) * PS + ky * ROW_US + (n + kx) * SITE_US;
    }
    size_t obase[4];
    const int oxv = x0 + wave * 16 + n;
    const bool oxok = oxv < OW;
    #pragma unroll
    for (int j = 0; j < 4; ++j)
        obase[j] = ((size_t)(ni * CO + quad * 4 + j)) * OH * OW + oxv;

    // ---- stage, phase 2: pack to bf16 planes and write LDS ----
    if (active) {
        ushort* d = &lds[(yy * TIN_XS + qx * 4) * SITE_US];
        #pragma unroll
        for (int j = 0; j < 4; ++j) {
            ushort* d0 = d + j * SITE_US;
            *(uint4*)d0 = make_uint4(pkbf(v[0][j],  v[1][j]),  pkbf(v[2][j],  v[3][j]),
                                     pkbf(v[4][j],  v[5][j]),  pkbf(v[6][j],  v[7][j]));
            *(uint4*)(d0 + PS) = make_uint4(pkbf(v[8][j],  v[9][j]),  pkbf(v[10][j], v[11][j]),
                                            pkbf(v[12][j], v[13][j]), pkbf(v[14][j], v[15][j]));
        }
    }
    __syncthreads();

    // ---- K-loop per output-row pair: 10 ds_read_b128 + 10 MFMA ----
    const ushort* wcol = lds + wave * 16 * SITE_US;
    #pragma unroll 1
    for (int r = 0; r < TY; r += 2) {
        floatx4 acc0 = {0.f, 0.f, 0.f, 0.f};
        floatx4 acc1 = {0.f, 0.f, 0.f, 0.f};
        const ushort* b0 = wcol + r * ROW_US;
        const ushort* b1 = b0 + ROW_US;
        #pragma unroll
        for (int c = 0; c < 5; ++c) {
            const short8 f0 = *(const short8*)(b0 + boff[c]);
            const short8 f1 = *(const short8*)(b1 + boff[c]);
            acc0 = __builtin_amdgcn_mfma_f32_16x16x32_bf16(afrag[c], f0, acc0, 0, 0, 0);
            acc1 = __builtin_amdgcn_mfma_f32_16x16x32_bf16(afrag[c], f1, acc1, 0, 0, 0);
        }
        // epilogue: D col = lane&15 = pix, row = quad*4+reg = co
        #pragma unroll
        for (int rr = 0; rr < 2; ++rr) {
            const int oy = y0 + r + rr;
            if (oy < OH && oxok) {
                const floatx4 av = rr ? acc1 : acc0;
                #pragma unroll
                for (int j = 0; j < 4; ++j) {
                    const float v2 = av[j] + bias_j[j];
                    const float vc = fminf(v2, 15.0f);       // tanh saturated beyond
                    const float e  = __expf(vc);
                    const float z  = 1.0f + e;
                    const float z2 = z * z;
                    const float t  = __fdividef(z2 - 1.0f, z2 + 1.0f);
                    out[obase[j] + (size_t)oy * OW] = v2 * t; // mish
                }
            }
        }
    }
}

extern "C" void kernel_launch(void* const* d_in, const int* in_sizes, int n_in,
                              void* d_out, int out_size, void* d_ws, size_t ws_size,
                              hipStream_t stream) {
    const float* x = (const float*)d_in[0];
    const float* w = (const float*)d_in[1];
    const float* b = (const float*)d_in[2];
    float* out = (float*)d_out;
    ushort* wr = (ushort*)d_ws;   // 2560*2 + 16*4 = 5184 bytes

    hipLaunchKernelGGL(reorder_weights, dim3(1), dim3(256), 0, stream, w, b, wr);

    dim3 grid(OW / TX + 1, (OH + TY - 1) / TY, N);   // 4 x 26 x 32
    hipLaunchKernelGGL(conv_mfma, grid, dim3(256), 0, stream, x, wr, out);
}

// Round 6
// 286.459 us; speedup vs baseline: 1.0086x; 1.0086x over previous
//
#include <hip/hip_runtime.h>
#include <hip/hip_bf16.h>

// Problem constants
constexpr int N   = 32;
constexpr int C   = 16;    // in channels
constexpr int H   = 256;
constexpr int W   = 256;
constexpr int CO  = 16;    // out channels
constexpr int OH  = 254;
constexpr int OW  = 254;
constexpr float SUBV = 0.7f;   // SUB1 + SUB2

// GEMM-view: k = (ky*3+kx)*16 + ci, K=144 padded to 160 (5 chunks of 32)
constexpr int KPAD = 160;

// Fast-path tiling
constexpr int TY     = 10;                 // output rows per block
constexpr int TIN_Y  = TY + 2;             // 12 staged input rows
constexpr int TX     = 64;                 // output px per block (4 waves x 16)
constexpr int TIN_XS = 68;                 // staged sites per row (66 needed)
constexpr int SITE_US = 16;                // 32 B per site: 16 ci bf16 interleaved
constexpr int ROW_US  = TIN_XS * SITE_US;  // 1088 ushorts per row
constexpr int NCHUNK  = 26;                // ceil(12*1088*2 / 1024) 1KB DMA chunks
constexpr int LDS_US  = NCHUNK * 512;      // 13312 ushorts = 26624 B (pad incl.)

constexpr size_t XB_BYTES = (size_t)N * H * W * C * 2;   // 64 MiB bf16 NHWC

using short8  = __attribute__((ext_vector_type(8))) short;
using floatx4 = __attribute__((ext_vector_type(4))) float;

__device__ inline uint bf16u(float f) {           // RNE float->bf16 bits (inputs are finite)
    uint u = __builtin_bit_cast(uint, f);
    u += 0x7fffu + ((u >> 16) & 1u);
    return u >> 16;
}
__device__ inline uint pkbf(float lo, float hi) { // v_cvt_pk_bf16_f32 (RNE), lo in low 16
    __hip_bfloat162 h = __float22bfloat162_rn(make_float2(lo, hi));
    uint r;
    __builtin_memcpy(&r, &h, sizeof(r));
    return r;
}
// 16B global->LDS DMA: per-lane global src, wave-uniform LDS base + lane*16.
__device__ inline void load_lds16(const void* g, void* l) {
    __builtin_amdgcn_global_load_lds(
        (const __attribute__((address_space(1))) void*)g,
        (__attribute__((address_space(3))) void*)l, 16, 0, 0);
}

// ---------------------------------------------------------------------------
// Kernel 1: weights -> bf16, k-reordered A-matrix [co][KPAD]; k<144 real, rest 0.
// Bias (fp32, -0.7 folded) appended at ushort offset 2560 (byte 5120).
// ---------------------------------------------------------------------------
__global__ void reorder_weights(const float* __restrict__ w,
                                const float* __restrict__ b,
                                ushort* __restrict__ wr) {
    const int t = threadIdx.x;
    for (int i = t; i < CO * KPAD; i += 256) {
        const int co = i / KPAD;
        const int k  = i - co * KPAD;
        ushort v = 0;
        if (k < 144) {
            const int pair = k >> 4;          // ky*3+kx, 0..8
            const int ci   = k & 15;
            const int ky   = pair / 3;
            const int kx   = pair - 3 * ky;
            v = (ushort)bf16u(w[((co * C + ci) * 3 + ky) * 3 + kx]);
        }
        wr[i] = v;
    }
    if (t < CO) ((float*)(wr + CO * KPAD))[t] = b[t] - SUBV;
}

// ---------------------------------------------------------------------------
// Kernel 2 (fast path): transpose+convert x [N][C][H][W] fp32 -> xb [N][H][W][C]
// bf16. Barrier-free, 32 waves/CU: TLP hides latency (streaming regime).
// Thread t handles 2 consecutive x-sites: 16 strided float2 reads (each stream
// coalesced across lanes), 64 B contiguous write.
// ---------------------------------------------------------------------------
__launch_bounds__(256)
__global__ void convert_x(const float* __restrict__ x, ushort* __restrict__ xb) {
    const size_t t = (size_t)blockIdx.x * 256 + threadIdx.x;   // < 1048576
    const int ni = (int)(t >> 15);            // / (256*256/2)
    const int sp = (int)(t & 32767);
    const int y  = sp >> 7;
    const int xp = (sp & 127) << 1;
    const float* src = x + ((size_t)ni * C * H) * W + (size_t)y * W + xp;
    float px[16], py[16];
    #pragma unroll
    for (int ci = 0; ci < C; ++ci) {
        const float2 p = *(const float2*)(src + (size_t)ci * H * W);
        px[ci] = p.x; py[ci] = p.y;
    }
    uint4* dst = (uint4*)(xb + t * 32);
    dst[0] = make_uint4(pkbf(px[0],px[1]),  pkbf(px[2],px[3]),
                        pkbf(px[4],px[5]),  pkbf(px[6],px[7]));
    dst[1] = make_uint4(pkbf(px[8],px[9]),  pkbf(px[10],px[11]),
                        pkbf(px[12],px[13]),pkbf(px[14],px[15]));
    dst[2] = make_uint4(pkbf(py[0],py[1]),  pkbf(py[2],py[3]),
                        pkbf(py[4],py[5]),  pkbf(py[6],py[7]));
    dst[3] = make_uint4(pkbf(py[8],py[9]),  pkbf(py[10],py[11]),
                        pkbf(py[12],py[13]),pkbf(py[14],py[15]));
}

// ---------------------------------------------------------------------------
// Kernel 3 (fast path): implicit-GEMM conv3x3, staging via global_load_lds DMA.
// LDS [yy][xx][ci] bf16, 32 B/site, linear. 26x 1KB chunks per block; loads
// consume no VGPRs -> full 26 KB in flight per block, 6 blocks/CU.
// K-loop ds_read_b128 pattern: 1 lane per 16B granule -> conflict-free.
// ---------------------------------------------------------------------------
__launch_bounds__(256, 6)
__global__ void conv_mfma2(const ushort* __restrict__ xb,
                           const ushort* __restrict__ wr,
                           float* __restrict__ out) {
    __shared__ ushort lds[LDS_US];           // 26624 B

    const int tid  = threadIdx.x;
    const int lane = tid & 63;
    const int wave = tid >> 6;
    const int quad = lane >> 4;
    const int n    = lane & 15;

    const int x0 = blockIdx.x * TX;
    const int y0 = blockIdx.y * TY;
    const int ni = blockIdx.z;

    // ---- stage: issue all DMA chunks (no VGPR results, all stay in flight) ----
    for (int c = wave; c < NCHUNK; c += 4) {
        const int S  = c * 32 + (lane >> 1);             // site linear index 0..831
        const int h  = lane & 1;                         // ci-half (16B)
        const int yy = S / TIN_XS;
        const int xx = S - TIN_XS * yy;
        const int iy = min(y0 + yy, H - 1);              // clamped cells feed only masked outputs
        const int ix = min(x0 + xx, W - 1);
        const ushort* src = xb + (((size_t)ni * H + iy) * W + ix) * 16 + h * 8;
        load_lds16(src, (char*)lds + c * 1024);          // LDS base wave-uniform
    }

    // ---- per-lane A fragments / bias / offsets (overlaps DMA latency) ----
    short8 afrag[5];
    {
        const ushort* wbase = wr + n * KPAD + quad * 8;   // A[m=co=n][k=32c+8*quad+j]
        #pragma unroll
        for (int c = 0; c < 5; ++c)
            afrag[c] = *(const short8*)(wbase + c * 32);
    }
    float bias_j[4];
    {
        const float* bp = (const float*)(wr + CO * KPAD);
        const float4 bv = *(const float4*)(bp + quad * 4);
        bias_j[0] = bv.x; bias_j[1] = bv.y; bias_j[2] = bv.z; bias_j[3] = bv.w;
    }
    int boff[5];
    #pragma unroll
    for (int c = 0; c < 5; ++c) {
        int pair = 2 * c + (quad >> 1);
        if (pair > 8) pair = 8;              // pad chunk reads real data x zero weights
        const int ky = pair / 3;
        const int kx = pair - 3 * ky;
        boff[c] = ky * ROW_US + (n + kx) * SITE_US + (quad & 1) * 8;
    }
    size_t obase[4];
    const int oxv = x0 + wave * 16 + n;
    const bool oxok = oxv < OW;
    #pragma unroll
    for (int j = 0; j < 4; ++j)
        obase[j] = ((size_t)(ni * CO + quad * 4 + j)) * OH * OW + oxv;

    __syncthreads();                          // drains vmcnt (DMA complete)

    // ---- K-loop per output-row pair: 10 ds_read_b128 + 10 MFMA ----
    const ushort* wcol = lds + wave * 16 * SITE_US;
    #pragma unroll 1
    for (int r = 0; r < TY; r += 2) {
        floatx4 acc0 = {0.f, 0.f, 0.f, 0.f};
        floatx4 acc1 = {0.f, 0.f, 0.f, 0.f};
        const ushort* b0 = wcol + r * ROW_US;
        const ushort* b1 = b0 + ROW_US;
        #pragma unroll
        for (int c = 0; c < 5; ++c) {
            const short8 f0 = *(const short8*)(b0 + boff[c]);
            const short8 f1 = *(const short8*)(b1 + boff[c]);
            acc0 = __builtin_amdgcn_mfma_f32_16x16x32_bf16(afrag[c], f0, acc0, 0, 0, 0);
            acc1 = __builtin_amdgcn_mfma_f32_16x16x32_bf16(afrag[c], f1, acc1, 0, 0, 0);
        }
        // epilogue: D col = lane&15 = pix, row = quad*4+reg = co
        #pragma unroll
        for (int rr = 0; rr < 2; ++rr) {
            const int oy = y0 + r + rr;
            if (oy < OH && oxok) {
                const floatx4 av = rr ? acc1 : acc0;
                #pragma unroll
                for (int j = 0; j < 4; ++j) {
                    const float v2 = av[j] + bias_j[j];
                    const float vc = fminf(v2, 15.0f);       // tanh saturated beyond
                    const float e  = __expf(vc);
                    const float z  = 1.0f + e;
                    const float z2 = z * z;
                    const float t  = __fdividef(z2 - 1.0f, z2 + 1.0f);
                    out[obase[j] + (size_t)oy * OW] = v2 * t; // mish
                }
            }
        }
    }
}

// ---------------------------------------------------------------------------
// Fallback (ws too small): round-3 verified kernel (register staging).
// ---------------------------------------------------------------------------
__launch_bounds__(256, 4)
__global__ void conv_mfma_fb(const float* __restrict__ x,
                             const ushort* __restrict__ wr,
                             float* __restrict__ out) {
    __shared__ ushort lds[2 * 6528];         // plane-separated layout, 26112 B

    const int tid  = threadIdx.x;
    const int lane = tid & 63;
    const int wave = tid >> 6;
    const int quad = lane >> 4;
    const int n    = lane & 15;

    const int x0 = blockIdx.x * TX;
    const int y0 = blockIdx.y * TY;
    const int ni = blockIdx.z;

    const bool active = tid < TIN_Y * (TIN_XS / 4);   // 204 threads
    int yy = 0, qx = 0;
    float4 v[16];
    if (active) {
        yy = tid / 17;
        qx = tid - yy * 17;
        const int iy = (y0 + yy < H - 1) ? (y0 + yy) : (H - 1);
        int bx = x0 + qx * 4;
        if (bx > W - 4) bx = W - 4;
        const float* src = x + (size_t)ni * C * H * W + (size_t)iy * W + bx;
        #pragma unroll
        for (int ci = 0; ci < C; ++ci)
            v[ci] = *(const float4*)(src + (size_t)ci * H * W);
    }

    short8 afrag[5];
    {
        const ushort* wbase = wr + n * KPAD + quad * 8;
        #pragma unroll
        for (int c = 0; c < 5; ++c)
            afrag[c] = *(const short8*)(wbase + c * 32);
    }
    float bias_j[4];
    {
        const float* bp = (const float*)(wr + CO * KPAD);
        const float4 bv = *(const float4*)(bp + quad * 4);
        bias_j[0] = bv.x; bias_j[1] = bv.y; bias_j[2] = bv.z; bias_j[3] = bv.w;
    }
    int boff[5];
    #pragma unroll
    for (int c = 0; c < 5; ++c) {
        int pair = 2 * c + (quad >> 1);
        if (pair > 8) pair = 8;
        const int ky = pair / 3;
        const int kx = pair - 3 * ky;
        boff[c] = (quad & 1) * 6528 + ky * 544 + (n + kx) * 8;
    }
    size_t obase[4];
    const int oxv = x0 + wave * 16 + n;
    const bool oxok = oxv < OW;
    #pragma unroll
    for (int j = 0; j < 4; ++j)
        obase[j] = ((size_t)(ni * CO + quad * 4 + j)) * OH * OW + oxv;

    if (active) {
        ushort* d = &lds[(yy * TIN_XS + qx * 4) * 8];
        #pragma unroll
        for (int j = 0; j < 4; ++j) {
            ushort* d0 = d + j * 8;
            *(uint4*)d0 = make_uint4(pkbf(v[0][j],  v[1][j]),  pkbf(v[2][j],  v[3][j]),
                                     pkbf(v[4][j],  v[5][j]),  pkbf(v[6][j],  v[7][j]));
            *(uint4*)(d0 + 6528) = make_uint4(pkbf(v[8][j],  v[9][j]),  pkbf(v[10][j], v[11][j]),
                                              pkbf(v[12][j], v[13][j]), pkbf(v[14][j], v[15][j]));
        }
    }
    __syncthreads();

    const ushort* wcol = lds + wave * 16 * 8;
    #pragma unroll 1
    for (int r = 0; r < TY; r += 2) {
        floatx4 acc0 = {0.f, 0.f, 0.f, 0.f};
        floatx4 acc1 = {0.f, 0.f, 0.f, 0.f};
        const ushort* b0 = wcol + r * 544;
        const ushort* b1 = b0 + 544;
        #pragma unroll
        for (int c = 0; c < 5; ++c) {
            const short8 f0 = *(const short8*)(b0 + boff[c]);
            const short8 f1 = *(const short8*)(b1 + boff[c]);
            acc0 = __builtin_amdgcn_mfma_f32_16x16x32_bf16(afrag[c], f0, acc0, 0, 0, 0);
            acc1 = __builtin_amdgcn_mfma_f32_16x16x32_bf16(afrag[c], f1, acc1, 0, 0, 0);
        }
        #pragma unroll
        for (int rr = 0; rr < 2; ++rr) {
            const int oy = y0 + r + rr;
            if (oy < OH && oxok) {
                const floatx4 av = rr ? acc1 : acc0;
                #pragma unroll
                for (int j = 0; j < 4; ++j) {
                    const float v2 = av[j] + bias_j[j];
                    const float vc = fminf(v2, 15.0f);
                    const float e  = __expf(vc);
                    const float z  = 1.0f + e;
                    const float z2 = z * z;
                    const float t  = __fdividef(z2 - 1.0f, z2 + 1.0f);
                    out[obase[j] + (size_t)oy * OW] = v2 * t;
                }
            }
        }
    }
}

extern "C" void kernel_launch(void* const* d_in, const int* in_sizes, int n_in,
                              void* d_out, int out_size, void* d_ws, size_t ws_size,
                              hipStream_t stream) {
    const float* x = (const float*)d_in[0];
    const float* w = (const float*)d_in[1];
    const float* b = (const float*)d_in[2];
    float* out = (float*)d_out;

    const size_t need = XB_BYTES + 5184;
    if (ws_size >= need) {
        ushort* xb = (ushort*)d_ws;
        ushort* wr = (ushort*)((char*)d_ws + XB_BYTES);
        hipLaunchKernelGGL(reorder_weights, dim3(1), dim3(256), 0, stream, w, b, wr);
        hipLaunchKernelGGL(convert_x, dim3((N * H * W / 2) / 256), dim3(256), 0, stream, x, xb);
        dim3 grid(OW / TX + 1, (OH + TY - 1) / TY, N);   // 4 x 26 x 32
        hipLaunchKernelGGL(conv_mfma2, grid, dim3(256), 0, stream, xb, wr, out);
    } else {
        ushort* wr = (ushort*)d_ws;                       // 5184 bytes
        hipLaunchKernelGGL(reorder_weights, dim3(1), dim3(256), 0, stream, w, b, wr);
        dim3 grid(OW / TX + 1, (OH + TY - 1) / TY, N);
        hipLaunchKernelGGL(conv_mfma_fb, grid, dim3(256), 0, stream, x, wr, out);
    }
}

// Round 7
// 283.171 us; speedup vs baseline: 1.0203x; 1.0116x over previous
//
#include <hip/hip_runtime.h>
#include <hip/hip_bf16.h>

// Problem constants
constexpr int N   = 32;
constexpr int C   = 16;    // in channels
constexpr int H   = 256;
constexpr int W   = 256;
constexpr int CO  = 16;    // out channels
constexpr int OH  = 254;
constexpr int OW  = 254;
constexpr float SUBV = 0.7f;   // SUB1 + SUB2

// GEMM-view: k = (ky*3+kx)*16 + ci, K=144 padded to 160 (5 chunks of 32)
constexpr int KPAD = 160;

// Tiling: TY=6 so fp32 scratch + bf16 tile fit 3 blocks/CU
constexpr int TY     = 6;                  // output rows per block
constexpr int TIN_Y  = TY + 2;             // 8 staged input rows
constexpr int TX     = 64;                 // output px per block (4 waves x 16)
constexpr int TIN_XS = 68;                 // staged sites per row (66 needed)
// bf16 tile [yy][xx][ci], 32 B/site (identical to verified round-6 layout)
constexpr int SITE_US = 16;                // ushorts per site
constexpr int ROW_US  = TIN_XS * SITE_US;  // 1088 ushorts per row
constexpr int BF_US   = TIN_Y * ROW_US;    // 8704 ushorts = 17408 B
// fp32 scratch [ci][yy][68 floats], row padded to 17x16B chunks
constexpr int FROW_CH   = 17;                  // 16B chunks per row (68 floats)
constexpr int FPLANE_CH = TIN_Y * FROW_CH;     // 136 chunks per ci-plane
constexpr int F_CH      = C * FPLANE_CH;       // 2176 chunks = 34816 B
constexpr int FPL_F     = FPLANE_CH * 4;       // plane stride in floats (544)
// total LDS = 34816 + 17408 = 52224 B -> 3 blocks/CU

using short8  = __attribute__((ext_vector_type(8))) short;
using floatx4 = __attribute__((ext_vector_type(4))) float;

__device__ inline uint bf16u(float f) {           // RNE float->bf16 bits (inputs are finite)
    uint u = __builtin_bit_cast(uint, f);
    u += 0x7fffu + ((u >> 16) & 1u);
    return u >> 16;
}
__device__ inline uint pkbf(float lo, float hi) { // v_cvt_pk_bf16_f32 (RNE), lo in low 16
    __hip_bfloat162 h = __float22bfloat162_rn(make_float2(lo, hi));
    uint r;
    __builtin_memcpy(&r, &h, sizeof(r));
    return r;
}
// 16B global->LDS DMA: per-lane global src, wave-uniform LDS base + lane*16.
__device__ inline void load_lds16(const void* g, void* l) {
    __builtin_amdgcn_global_load_lds(
        (const __attribute__((address_space(1))) void*)g,
        (__attribute__((address_space(3))) void*)l, 16, 0, 0);
}

// ---------------------------------------------------------------------------
// Kernel 1: weights -> bf16, k-reordered A-matrix [co][KPAD]; k<144 real, rest 0.
// Bias (fp32, -0.7 folded) appended at ushort offset 2560 (byte 5120).
// ---------------------------------------------------------------------------
__global__ void reorder_weights(const float* __restrict__ w,
                                const float* __restrict__ b,
                                ushort* __restrict__ wr) {
    const int t = threadIdx.x;
    for (int i = t; i < CO * KPAD; i += 256) {
        const int co = i / KPAD;
        const int k  = i - co * KPAD;
        ushort v = 0;
        if (k < 144) {
            const int pair = k >> 4;          // ky*3+kx, 0..8
            const int ci   = k & 15;
            const int ky   = pair / 3;
            const int kx   = pair - 3 * ky;
            v = (ushort)bf16u(w[((co * C + ci) * 3 + ky) * 3 + kx]);
        }
        wr[i] = v;
    }
    if (t < CO) ((float*)(wr + CO * KPAD))[t] = b[t] - SUBV;
}

// ---------------------------------------------------------------------------
// Kernel 2: fused implicit-GEMM conv3x3 + bias + mish, fp32 DMA staging.
// Phase 1: DMA fp32 CHW tile (34 KB, linear LDS, per-lane global src).
// Phase 2: in-LDS repack fp32 CHW -> bf16 [yy][xx][ci] (2-way reads, b128
//          writes, cvt_pk) -- same verified tile the K-loop consumed in r6.
// Phase 3: K-loop 10 ds_read_b128 + 10 MFMA per row-pair, fused epilogue.
// 52224 B LDS -> 3 blocks/CU; DMA consumes no VGPRs -> 102 KB/CU in flight.
// ---------------------------------------------------------------------------
__launch_bounds__(256, 3)
__global__ void conv_fused(const float* __restrict__ x,
                           const ushort* __restrict__ wr,
                           float* __restrict__ out) {
    __shared__ float  lds_f[F_CH * 4];       // 34816 B fp32 scratch
    __shared__ ushort lds_bf[BF_US];         // 17408 B bf16 tile

    const int tid  = threadIdx.x;
    const int lane = tid & 63;
    const int wave = tid >> 6;
    const int quad = lane >> 4;
    const int n    = lane & 15;

    const int x0 = blockIdx.x * TX;
    const int y0 = blockIdx.y * TY;
    const int ni = blockIdx.z;

    // ---- phase 1: issue all 34 DMA chunks (zero VGPR results) ----
    {
        const float* xs = x + (size_t)ni * C * H * W;
        for (int c = wave; c < F_CH / 64; c += 4) {      // 34 wave-chunks
            const int L   = c * 64 + lane;               // 16B-chunk linear idx
            const int ci  = L / FPLANE_CH;
            const int rem = L - ci * FPLANE_CH;
            const int yy  = rem / FROW_CH;
            const int q   = rem - yy * FROW_CH;
            const int iy  = min(y0 + yy, H - 1);         // clamped rows feed only masked oy
            const int ix  = min(x0 + 4 * q, W - 4);      // clamped cols feed only masked ox
            const float* src = xs + ((size_t)ci * H + iy) * W + ix;
            load_lds16(src, (char*)lds_f + c * 1024);    // LDS base wave-uniform
        }
    }

    // ---- per-lane A fragments / bias / offsets (overlaps DMA latency) ----
    short8 afrag[5];
    {
        const ushort* wbase = wr + n * KPAD + quad * 8;   // A[m=co=n][k=32c+8*quad+j]
        #pragma unroll
        for (int c = 0; c < 5; ++c)
            afrag[c] = *(const short8*)(wbase + c * 32);
    }
    float bias_j[4];
    {
        const float* bp = (const float*)(wr + CO * KPAD);
        const float4 bv = *(const float4*)(bp + quad * 4);
        bias_j[0] = bv.x; bias_j[1] = bv.y; bias_j[2] = bv.z; bias_j[3] = bv.w;
    }
    int boff[5];
    #pragma unroll
    for (int c = 0; c < 5; ++c) {
        int pair = 2 * c + (quad >> 1);
        if (pair > 8) pair = 8;              // pad chunk reads real data x zero weights
        const int ky = pair / 3;
        const int kx = pair - 3 * ky;
        boff[c] = ky * ROW_US + (n + kx) * SITE_US + (quad & 1) * 8;
    }
    size_t obase[4];
    const int oxv = x0 + wave * 16 + n;
    const bool oxok = oxv < OW;
    #pragma unroll
    for (int j = 0; j < 4; ++j)
        obase[j] = ((size_t)(ni * CO + quad * 4 + j)) * OH * OW + oxv;

    __syncthreads();                          // DMA drained (vmcnt 0)

    // ---- phase 2: repack fp32 CHW -> bf16 [yy][xx][ci] ----
    // item = half-site (site, ci-half h). Reads: 8 b32, plane-strided (544 fl
    // = bank-aligned, lanes pair 2-way = free). Writes: consecutive lanes ->
    // consecutive 16B -> conflict-free b128.
    for (int it = tid; it < TIN_Y * TIN_XS * 2; it += 256) {   // 1088 items
        const int s  = it >> 1;
        const int h  = it & 1;
        const int yy = s / TIN_XS;
        const int xx = s - yy * TIN_XS;
        const float* fp = lds_f + (8 * h) * FPL_F + yy * (FROW_CH * 4) + xx;
        float f[8];
        #pragma unroll
        for (int j = 0; j < 8; ++j)
            f[j] = fp[j * FPL_F];
        *(uint4*)(lds_bf + (size_t)it * 8) =
            make_uint4(pkbf(f[0], f[1]), pkbf(f[2], f[3]),
                       pkbf(f[4], f[5]), pkbf(f[6], f[7]));
    }
    __syncthreads();

    // ---- phase 3: K-loop per output-row pair: 10 ds_read_b128 + 10 MFMA ----
    const ushort* wcol = lds_bf + wave * 16 * SITE_US;
    #pragma unroll 1
    for (int r = 0; r < TY; r += 2) {
        floatx4 acc0 = {0.f, 0.f, 0.f, 0.f};
        floatx4 acc1 = {0.f, 0.f, 0.f, 0.f};
        const ushort* b0 = wcol + r * ROW_US;
        const ushort* b1 = b0 + ROW_US;
        #pragma unroll
        for (int c = 0; c < 5; ++c) {
            const short8 f0 = *(const short8*)(b0 + boff[c]);
            const short8 f1 = *(const short8*)(b1 + boff[c]);
            acc0 = __builtin_amdgcn_mfma_f32_16x16x32_bf16(afrag[c], f0, acc0, 0, 0, 0);
            acc1 = __builtin_amdgcn_mfma_f32_16x16x32_bf16(afrag[c], f1, acc1, 0, 0, 0);
        }
        // epilogue: D col = lane&15 = pix, row = quad*4+reg = co
        #pragma unroll
        for (int rr = 0; rr < 2; ++rr) {
            const int oy = y0 + r + rr;
            if (oy < OH && oxok) {
                const floatx4 av = rr ? acc1 : acc0;
                #pragma unroll
                for (int j = 0; j < 4; ++j) {
                    const float v2 = av[j] + bias_j[j];
                    const float vc = fminf(v2, 15.0f);       // tanh saturated beyond
                    const float e  = __expf(vc);
                    const float z  = 1.0f + e;
                    const float z2 = z * z;
                    const float t  = __fdividef(z2 - 1.0f, z2 + 1.0f);
                    out[obase[j] + (size_t)oy * OW] = v2 * t; // mish
                }
            }
        }
    }
}

extern "C" void kernel_launch(void* const* d_in, const int* in_sizes, int n_in,
                              void* d_out, int out_size, void* d_ws, size_t ws_size,
                              hipStream_t stream) {
    const float* x = (const float*)d_in[0];
    const float* w = (const float*)d_in[1];
    const float* b = (const float*)d_in[2];
    float* out = (float*)d_out;
    ushort* wr = (ushort*)d_ws;   // 2560*2 + 16*4 = 5184 bytes

    hipLaunchKernelGGL(reorder_weights, dim3(1), dim3(256), 0, stream, w, b, wr);

    dim3 grid(OW / TX + 1, (OH + TY - 1) / TY, N);   // 4 x 43 x 32
    hipLaunchKernelGGL(conv_fused, grid, dim3(256), 0, stream, x, wr, out);
}